// Round 2
// 490.097 us; speedup vs baseline: 1.1523x; 1.1523x over previous
//
#include <hip/hip_runtime.h>
#include <hip/hip_bf16.h>
#include <stdint.h>

typedef _Float16 f16;
typedef _Float16 f16x8 __attribute__((ext_vector_type(8)));
typedef float f32x4 __attribute__((ext_vector_type(4)));

#define N_FEAT 4096
#define M_ROWS 8192
#define QSTRIDE 512  // IN_FEATURES / 8 codewords per W row

// Async global->LDS, 16B per lane: wave-uniform LDS base, HW adds lane*16.
#define GLD16(gptr, lptr)                                                      \
  __builtin_amdgcn_global_load_lds(                                            \
      (const __attribute__((address_space(1))) void*)(gptr),                   \
      (__attribute__((address_space(3))) void*)(uint32_t)(uintptr_t)(lptr),    \
      16, 0, 0)

// Pad 4 floats per 64: keeps 16B alignment of 4-float groups, <=2-way banks.
#define PAD64(i) ((i) + (((i) >> 6) << 2))

// 4-stage in-register Hadamard butterfly on 16 elements (unnormalized).
__device__ __forceinline__ void fht16(float v[16]) {
#pragma unroll
  for (int h = 1; h < 16; h <<= 1) {
#pragma unroll
    for (int i = 0; i < 16; i += (h << 1)) {
#pragma unroll
      for (int j = 0; j < h; ++j) {
        float a = v[i + j], b = v[i + j + h];
        v[i + j] = a + b;
        v[i + j + h] = a - b;
      }
    }
  }
}

__device__ __forceinline__ void fht4(float& a, float& b, float& c, float& d) {
  float t0 = a + b, t1 = a - b, t2 = c + d, t3 = c - d;
  a = t0 + t2; b = t1 + t3; c = t0 - t2; d = t1 - t3;
}

// ---------------------------------------------------------------------------
// Kernel 1: x = f16( FHT(input*SU) * Wscale/64 ), one 4096-row per block.
// ---------------------------------------------------------------------------
__global__ __launch_bounds__(256) void k_fht_in(const float* __restrict__ x,
                                                const float* __restrict__ SU,
                                                const float* __restrict__ wscale,
                                                f16* __restrict__ out) {
  __shared__ float lds[4096 + 256];
  const int row = blockIdx.x;
  const int t = threadIdx.x;
  const float* xr = x + (size_t)row * N_FEAT;
  float v[16];

#pragma unroll
  for (int j = 0; j < 4; ++j) {
    const float4 a = *(const float4*)(xr + (t << 4) + 4 * j);
    const float4 s = *(const float4*)(SU + (t << 4) + 4 * j);
    v[4 * j + 0] = a.x * s.x; v[4 * j + 1] = a.y * s.y;
    v[4 * j + 2] = a.z * s.z; v[4 * j + 3] = a.w * s.w;
  }
  fht16(v);
#pragma unroll
  for (int j = 0; j < 4; ++j)
    *(float4*)&lds[PAD64((t << 4) + 4 * j)] =
        make_float4(v[4 * j], v[4 * j + 1], v[4 * j + 2], v[4 * j + 3]);
  __syncthreads();

  const int a = t & 15, b = t >> 4;
#pragma unroll
  for (int j = 0; j < 16; ++j) v[j] = lds[PAD64((b << 8) + (j << 4) + a)];
  fht16(v);
#pragma unroll
  for (int j = 0; j < 16; ++j) lds[PAD64((b << 8) + (j << 4) + a)] = v[j];
  __syncthreads();

#pragma unroll
  for (int j = 0; j < 16; ++j) v[j] = lds[PAD64((j << 8) + t)];
  fht16(v);
  const float s = wscale[0] * 0.015625f;  // 1/sqrt(4096) = 1/64
  f16* op = out + (size_t)row * N_FEAT;
#pragma unroll
  for (int j = 0; j < 16; ++j) op[(j << 8) + t] = (f16)(v[j] * s);
}

// ---------------------------------------------------------------------------
// Kernel 2: pass A of W' = H*W — decode e8p codes, H64 over low 6 bits of n.
// ---------------------------------------------------------------------------
__global__ __launch_bounds__(256) void k_wA(const int* __restrict__ q,
                                            const float* __restrict__ grid,
                                            f16* __restrict__ Wp) {
  __shared__ float tabf[2048];
  __shared__ float tile[64 * 65];
  const int t = threadIdx.x;
  const int kg = blockIdx.x;
  const int ng = blockIdx.y;
  {
    *(float4*)&tabf[t * 8] = *(const float4*)(grid + t * 8);
    *(float4*)&tabf[t * 8 + 4] = *(const float4*)(grid + t * 8 + 4);
  }
  __syncthreads();

#pragma unroll
  for (int e2 = 0; e2 < 2; ++e2) {
    const int e = t + (e2 << 8);
    const int nl = e >> 3, c = e & 7;
    const unsigned code =
        (unsigned)q[(size_t)(ng * 64 + nl) * QSTRIDE + kg * 8 + c] & 0xffffu;
    const float* tb = &tabf[(code & 255u) * 8];
#pragma unroll
    for (int j = 0; j < 8; ++j) {
      const int bi = __float_as_int(tb[j]) ^ (int)(((code >> (8 + j)) & 1u) << 31);
      tile[nl * 65 + (c << 3) + j] = __int_as_float(bi);
    }
  }
  __syncthreads();

  {
    const int k = t & 63, p = t >> 6;
    float v[16];
#pragma unroll
    for (int j = 0; j < 16; ++j) v[j] = tile[(16 * p + j) * 65 + k];
    fht16(v);
#pragma unroll
    for (int j = 0; j < 16; ++j) tile[(16 * p + j) * 65 + k] = v[j];
  }
  __syncthreads();

  {
    const int k = t & 63, base = (t >> 6) << 2;
#pragma unroll
    for (int bb = 0; bb < 4; ++bb) {
      const int low = base + bb;
      float v0 = tile[(low) * 65 + k],      v1 = tile[(low + 16) * 65 + k];
      float v2 = tile[(low + 32) * 65 + k], v3 = tile[(low + 48) * 65 + k];
      fht4(v0, v1, v2, v3);
      tile[(low) * 65 + k] = v0;      tile[(low + 16) * 65 + k] = v1;
      tile[(low + 32) * 65 + k] = v2; tile[(low + 48) * 65 + k] = v3;
    }
  }
  __syncthreads();

  {
    const int nl = t >> 2, koff = (t & 3) << 4;
    union { f16 h[16]; int4 v[2]; } u;
#pragma unroll
    for (int i = 0; i < 16; ++i) u.h[i] = (f16)tile[nl * 65 + koff + i];
    int4* dst = (int4*)(Wp + (size_t)(ng * 64 + nl) * N_FEAT + kg * 64 + koff);
    dst[0] = u.v[0];
    dst[1] = u.v[1];
  }
}

// ---------------------------------------------------------------------------
// Kernel 3: pass B — H64 over n bits 6..11, in place on Wp.
// ---------------------------------------------------------------------------
__global__ __launch_bounds__(256) void k_wB(f16* __restrict__ Wp) {
  __shared__ float tile[64 * 65];
  const int t = threadIdx.x;
  const int kg = blockIdx.x;
  const int n0 = blockIdx.y;
  {
    const int n1 = t >> 2, koff = (t & 3) << 4;
    const f16* src = Wp + (size_t)(n0 + 64 * n1) * N_FEAT + kg * 64 + koff;
    union { f16 h[16]; int4 v[2]; } u;
    u.v[0] = ((const int4*)src)[0];
    u.v[1] = ((const int4*)src)[1];
#pragma unroll
    for (int i = 0; i < 16; ++i) tile[n1 * 65 + koff + i] = (float)u.h[i];
  }
  __syncthreads();
  {
    const int k = t & 63, p = t >> 6;
    float v[16];
#pragma unroll
    for (int j = 0; j < 16; ++j) v[j] = tile[(16 * p + j) * 65 + k];
    fht16(v);
#pragma unroll
    for (int j = 0; j < 16; ++j) tile[(16 * p + j) * 65 + k] = v[j];
  }
  __syncthreads();
  {
    const int k = t & 63, base = (t >> 6) << 2;
#pragma unroll
    for (int bb = 0; bb < 4; ++bb) {
      const int low = base + bb;
      float v0 = tile[(low) * 65 + k],      v1 = tile[(low + 16) * 65 + k];
      float v2 = tile[(low + 32) * 65 + k], v3 = tile[(low + 48) * 65 + k];
      fht4(v0, v1, v2, v3);
      tile[(low) * 65 + k] = v0;      tile[(low + 16) * 65 + k] = v1;
      tile[(low + 32) * 65 + k] = v2; tile[(low + 48) * 65 + k] = v3;
    }
  }
  __syncthreads();
  {
    const int n1 = t >> 2, koff = (t & 3) << 4;
    union { f16 h[16]; int4 v[2]; } u;
#pragma unroll
    for (int i = 0; i < 16; ++i) u.h[i] = (f16)tile[n1 * 65 + koff + i];
    int4* dst = (int4*)(Wp + (size_t)(n0 + 64 * n1) * N_FEAT + kg * 64 + koff);
    dst[0] = u.v[0];
    dst[1] = u.v[1];
  }
}

// ---------------------------------------------------------------------------
// Kernel 4: out[8192,4096](fp32) = (x * W'^T)/64 * SV + bias.
// 256x256 tile, BK=64, 8 waves (2Mx4N), 4-phase K-tile schedule with counted
// vmcnt (never 0 in main loop), raw s_barrier, setprio around MFMA clusters.
//
// CRITICAL mapping invariant (round-1 bug): phase (mh,nh) must touch exactly
// one LDS half FOR EVERY WAVE. Half-select is therefore the TOP bit:
//   A rows:  m = (mh<<7) + (wr<<6) + (i<<4) + ml   (mh=0 -> h0, mh=1 -> h1)
//   B rows:  n = (nh<<7) + (wc<<5) + (j<<4) + ml   (nh=0 -> h2, nh=1 -> h3)
//
// Half-tiles per K-tile t, per-wave ISSUE ORDER h0, h2, h3, h1 (2 GLD16 each;
// order pinned by asm memory clobbers + sched_barrier(0) where no asm sits
// between groups).  Wait bookkeeping (per-wave outstanding, induction):
//   enter iter t:            {h3(t),h1(t)}                  = 4
//   P1 stage h0(t+1)         -> 6   (reads lo halves: landed)
//   W_P2 vmcnt(4): h3(t) done (B-hi readable)               -> 4
//   P2 stage h2(t+1)         -> 6
//   W_P3 vmcnt(4): h1(t) done (A-hi readable)               -> 4
//   P3 stage h3(t+1) -> 6;  P4 stage h1(t+1) -> 8
//   W_P4e vmcnt(4): h0,h2(t+1) done (next P1 readable)      -> 4
// Every LDS overwrite is >=1 barrier after its last reader (writes go to the
// nxt buffer; cur-buffer reads finished >=2 barriers before nxt->cur flip).
// ---------------------------------------------------------------------------
#define BM 256
#define BN 256
#define BK 64
#define KDIM 4096

#define WAITB(n)                                          \
  asm volatile("s_waitcnt vmcnt(" #n ")" ::: "memory");   \
  __builtin_amdgcn_s_barrier();

#define SCHED_FENCE() __builtin_amdgcn_sched_barrier(0)

// Stage one 128-row x 64-k half: wave w covers rows w*16+i*8..+7 (i=0,1).
// gbase points at (row 0 of the half, k-tile start). LDS base wave-uniform.
#define STAGE_HALF(gbase, lhalf)                                         \
  {                                                                      \
    _Pragma("unroll")                                                    \
    for (int i_ = 0; i_ < 2; ++i_) {                                     \
      const int rb_ = (w << 4) + (i_ << 3);                              \
      const int r_ = rb_ + srow;                                         \
      const int kc_ = scc ^ (r_ & 7);                                    \
      GLD16((gbase) + (size_t)r_ * KDIM + (kc_ << 3), (lhalf) + (rb_ << 6)); \
    }                                                                    \
  }

// A-fragments: 4 m-frags x 2 k-steps from m-half mh of current buffer.
#define LDA(dst, mh)                                                     \
  {                                                                      \
    _Pragma("unroll")                                                    \
    for (int i_ = 0; i_ < 4; ++i_) {                                     \
      const int m_ = ((mh) << 7) + (wr << 6) + (i_ << 4) + ml;           \
      _Pragma("unroll")                                                  \
      for (int s_ = 0; s_ < 2; ++s_) {                                   \
        const int kc_ = ((s_ << 2) + quad) ^ (m_ & 7);                   \
        dst[i_][s_] = *(const f16x8*)&sA[cur][(m_ << 6) + (kc_ << 3)];   \
      }                                                                  \
    }                                                                    \
  }

// B-fragments: 2 n-frags x 2 k-steps from n-half nh of current buffer.
#define LDB(dst, nh)                                                     \
  {                                                                      \
    _Pragma("unroll")                                                    \
    for (int j_ = 0; j_ < 2; ++j_) {                                     \
      const int n_ = ((nh) << 7) + (wc << 5) + (j_ << 4) + ml;           \
      _Pragma("unroll")                                                  \
      for (int s_ = 0; s_ < 2; ++s_) {                                   \
        const int kc_ = ((s_ << 2) + quad) ^ (n_ & 7);                   \
        dst[j_][s_] = *(const f16x8*)&sB[cur][(n_ << 6) + (kc_ << 3)];   \
      }                                                                  \
    }                                                                    \
  }

// One C-quadrant: 4m x 2n frags x 2 k-steps = 16 MFMA, setprio-wrapped.
#define MMAQ(mh, nh)                                                     \
  {                                                                      \
    __builtin_amdgcn_s_setprio(1);                                       \
    _Pragma("unroll")                                                    \
    for (int i_ = 0; i_ < 4; ++i_) {                                     \
      _Pragma("unroll")                                                  \
      for (int j_ = 0; j_ < 2; ++j_) {                                   \
        acc[(mh) * 4 + i_][(nh) * 2 + j_] =                              \
            __builtin_amdgcn_mfma_f32_16x16x32_f16(                      \
                af[i_][0], bf[j_][0], acc[(mh) * 4 + i_][(nh) * 2 + j_], \
                0, 0, 0);                                                \
        acc[(mh) * 4 + i_][(nh) * 2 + j_] =                              \
            __builtin_amdgcn_mfma_f32_16x16x32_f16(                      \
                af[i_][1], bf[j_][1], acc[(mh) * 4 + i_][(nh) * 2 + j_], \
                0, 0, 0);                                                \
      }                                                                  \
    }                                                                    \
    __builtin_amdgcn_s_setprio(0);                                       \
  }

__global__ __launch_bounds__(512, 2) void k_gemm(const f16* __restrict__ A,
                                                 const f16* __restrict__ B,
                                                 float* __restrict__ C,
                                                 const float* __restrict__ SV,
                                                 const float* __restrict__ bias) {
  __shared__ __attribute__((aligned(16))) f16 sA[2][BM * BK];
  __shared__ __attribute__((aligned(16))) f16 sB[2][BN * BK];

  const int tid = threadIdx.x;
  const int lane = tid & 63;
  const int w = tid >> 6;        // 0..7
  const int wr = w >> 2;         // 0..1 : 64-row band within each m-half
  const int wc = w & 3;          // 0..3 : 32-col band within each n-half
  const int m0 = blockIdx.y * BM;
  const int n0 = blockIdx.x * BN;
  const int quad = lane >> 4;
  const int ml = lane & 15;
  const int srow = lane >> 3;    // staging: row within 8-row group
  const int scc = lane & 7;      // staging: chunk (pre-swizzled at source)

  f32x4 acc[8][4];
#pragma unroll
  for (int i = 0; i < 8; ++i)
#pragma unroll
    for (int j = 0; j < 4; ++j) acc[i][j] = (f32x4)0.0f;

  const f16* Ab = A + (size_t)m0 * KDIM;
  const f16* Bb = B + (size_t)n0 * KDIM;

  // Prologue: stage tile 0, issue order h0, h2, h3, h1 (order pinned).
  STAGE_HALF(Ab, &sA[0][0]);                                  // h0(0) A-lo
  SCHED_FENCE();
  STAGE_HALF(Bb, &sB[0][0]);                                  // h2(0) B-lo
  SCHED_FENCE();
  STAGE_HALF(Bb + (size_t)128 * KDIM, &sB[0][128 * 64]);      // h3(0) B-hi
  SCHED_FENCE();
  STAGE_HALF(Ab + (size_t)128 * KDIM, &sA[0][128 * 64]);      // h1(0) A-hi
  WAITB(4);  // h0(0), h2(0) landed; h3(0), h1(0) in flight

  f16x8 af[4][2], bf[2][2];

#pragma unroll 2
  for (int t = 0; t < 64; ++t) {
    const int cur = t & 1;
    const int nxt = cur ^ 1;
    const int kn = ((t + 1) & 63) << 6;  // wrap-stage tile 0 on last iter
    const f16* An = Ab + kn;
    const f16* Bn = Bb + kn;

    // ---- P1: quadrant (m-lo, n-lo) — reads h0(t), h2(t) ----
    STAGE_HALF(An, &sA[nxt][0]);                              // h0(t+1)
    LDA(af, 0);
    LDB(bf, 0);
    MMAQ(0, 0);

    // ---- P2: quadrant (m-lo, n-hi) — unlocks h3(t) ----
    WAITB(4);
    STAGE_HALF(Bn, &sB[nxt][0]);                              // h2(t+1)
    LDB(bf, 1);
    MMAQ(0, 1);

    // ---- P3: quadrant (m-hi, n-hi) — unlocks h1(t) ----
    WAITB(4);
    STAGE_HALF(Bn + (size_t)128 * KDIM, &sB[nxt][128 * 64]);  // h3(t+1)
    LDA(af, 1);
    MMAQ(1, 1);

    // ---- P4: quadrant (m-hi, n-lo) ----
    SCHED_FENCE();  // pin h3(t+1) issue before h1(t+1) issue
    STAGE_HALF(An + (size_t)128 * KDIM, &sA[nxt][128 * 64]);  // h1(t+1)
    LDB(bf, 0);  // re-read n-lo frags (saves 16 VGPRs vs keeping live)
    MMAQ(1, 0);
    WAITB(4);                                                 // h0,h2(t+1)
  }

  // Drain the wrap-staged loads before LDS goes out of scope at endpgm.
  asm volatile("s_waitcnt vmcnt(0)" ::: "memory");

  // ---- epilogue: out = acc*(SV/64) + bias, fp32 stores ----
#pragma unroll
  for (int nj = 0; nj < 4; ++nj) {
    const int col = n0 + ((nj >> 1) << 7) + (wc << 5) + ((nj & 1) << 4) + ml;
    const float sv = SV[col] * 0.015625f;
    const float bs = bias[col];
#pragma unroll
    for (int mi = 0; mi < 8; ++mi) {
      const int rowb =
          m0 + ((mi >> 2) << 7) + (wr << 6) + ((mi & 3) << 4) + (quad << 2);
#pragma unroll
      for (int r = 0; r < 4; ++r)
        C[(size_t)(rowb + r) * N_FEAT + col] = acc[mi][nj][r] * sv + bs;
    }
  }
}

// ---------------------------------------------------------------------------
// Host. Buffer plan unchanged:
//   d_ws[0, 64MB)        : x (f16)
//   d_in[input]          : W' (f16) — input buffer reused post-FHT
//   d_out                : final fp32 output
// ---------------------------------------------------------------------------
extern "C" void kernel_launch(void* const* d_in, const int* in_sizes, int n_in,
                              void* d_out, int out_size, void* d_ws, size_t ws_size,
                              hipStream_t stream) {
  const float* input = nullptr;
  const int* qidxs = nullptr;
  const float* grid_abs = nullptr;
  const float* wscale = nullptr;
  const float* v4k[3] = {nullptr, nullptr, nullptr};
  int n4 = 0;
  for (int i = 0; i < n_in; ++i) {
    switch (in_sizes[i]) {
      case 33554432: input = (const float*)d_in[i]; break;
      case 2097152:  qidxs = (const int*)d_in[i]; break;
      case 2048:     grid_abs = (const float*)d_in[i]; break;
      case 1:        wscale = (const float*)d_in[i]; break;
      case 4096:     if (n4 < 3) v4k[n4++] = (const float*)d_in[i]; break;
      default: break;
    }
  }
  const float* SU = v4k[0];
  const float* SV = v4k[1];
  const float* bias = v4k[2];

  f16* x = (f16*)d_ws;
  f16* Wp = (f16*)const_cast<float*>(input);  // reuse input buffer post-FHT
  float* out = (float*)d_out;

  k_fht_in<<<M_ROWS, 256, 0, stream>>>(input, SU, wscale, x);
  dim3 gw(64, 64);
  k_wA<<<gw, 256, 0, stream>>>(qidxs, grid_abs, Wp);
  k_wB<<<gw, 256, 0, stream>>>(Wp);
  dim3 g(N_FEAT / BN, M_ROWS / BM);
  k_gemm<<<g, 512, 0, stream>>>(x, Wp, out, SV, bias);
}

// Round 3
// 486.828 us; speedup vs baseline: 1.1600x; 1.0067x over previous
//
#include <hip/hip_runtime.h>
#include <hip/hip_bf16.h>
#include <stdint.h>

typedef _Float16 f16;
typedef _Float16 f16x8 __attribute__((ext_vector_type(8)));
typedef float f32x4 __attribute__((ext_vector_type(4)));

#define N_FEAT 4096
#define M_ROWS 8192
#define QSTRIDE 512  // IN_FEATURES / 8 codewords per W row

// Async global->LDS, 16B per lane: wave-uniform LDS base, HW adds lane*16.
#define GLD16(gptr, lptr)                                                      \
  __builtin_amdgcn_global_load_lds(                                            \
      (const __attribute__((address_space(1))) void*)(gptr),                   \
      (__attribute__((address_space(3))) void*)(uint32_t)(uintptr_t)(lptr),    \
      16, 0, 0)

// Pad 4 floats per 64: keeps 16B alignment of 4-float groups, <=2-way banks.
#define PAD64(i) ((i) + (((i) >> 6) << 2))

// 4-stage in-register Hadamard butterfly on 16 elements (unnormalized).
__device__ __forceinline__ void fht16(float v[16]) {
#pragma unroll
  for (int h = 1; h < 16; h <<= 1) {
#pragma unroll
    for (int i = 0; i < 16; i += (h << 1)) {
#pragma unroll
      for (int j = 0; j < h; ++j) {
        float a = v[i + j], b = v[i + j + h];
        v[i + j] = a + b;
        v[i + j + h] = a - b;
      }
    }
  }
}

__device__ __forceinline__ void fht4(float& a, float& b, float& c, float& d) {
  float t0 = a + b, t1 = a - b, t2 = c + d, t3 = c - d;
  a = t0 + t2; b = t1 + t3; c = t0 - t2; d = t1 - t3;
}

// ---------------------------------------------------------------------------
// Kernel 1: x = f16( FHT(input*SU) * Wscale/64 ), one 4096-row per block.
// ---------------------------------------------------------------------------
__global__ __launch_bounds__(256) void k_fht_in(const float* __restrict__ x,
                                                const float* __restrict__ SU,
                                                const float* __restrict__ wscale,
                                                f16* __restrict__ out) {
  __shared__ float lds[4096 + 256];
  const int row = blockIdx.x;
  const int t = threadIdx.x;
  const float* xr = x + (size_t)row * N_FEAT;
  float v[16];

#pragma unroll
  for (int j = 0; j < 4; ++j) {
    const float4 a = *(const float4*)(xr + (t << 4) + 4 * j);
    const float4 s = *(const float4*)(SU + (t << 4) + 4 * j);
    v[4 * j + 0] = a.x * s.x; v[4 * j + 1] = a.y * s.y;
    v[4 * j + 2] = a.z * s.z; v[4 * j + 3] = a.w * s.w;
  }
  fht16(v);
#pragma unroll
  for (int j = 0; j < 4; ++j)
    *(float4*)&lds[PAD64((t << 4) + 4 * j)] =
        make_float4(v[4 * j], v[4 * j + 1], v[4 * j + 2], v[4 * j + 3]);
  __syncthreads();

  const int a = t & 15, b = t >> 4;
#pragma unroll
  for (int j = 0; j < 16; ++j) v[j] = lds[PAD64((b << 8) + (j << 4) + a)];
  fht16(v);
#pragma unroll
  for (int j = 0; j < 16; ++j) lds[PAD64((b << 8) + (j << 4) + a)] = v[j];
  __syncthreads();

#pragma unroll
  for (int j = 0; j < 16; ++j) v[j] = lds[PAD64((j << 8) + t)];
  fht16(v);
  const float s = wscale[0] * 0.015625f;  // 1/sqrt(4096) = 1/64
  f16* op = out + (size_t)row * N_FEAT;
#pragma unroll
  for (int j = 0; j < 16; ++j) op[(j << 8) + t] = (f16)(v[j] * s);
}

// ---------------------------------------------------------------------------
// Kernel 2: pass A of W' = H*W — decode e8p codes, H64 over low 6 bits of n.
// ---------------------------------------------------------------------------
__global__ __launch_bounds__(256) void k_wA(const int* __restrict__ q,
                                            const float* __restrict__ grid,
                                            f16* __restrict__ Wp) {
  __shared__ float tabf[2048];
  __shared__ float tile[64 * 65];
  const int t = threadIdx.x;
  const int kg = blockIdx.x;
  const int ng = blockIdx.y;
  {
    *(float4*)&tabf[t * 8] = *(const float4*)(grid + t * 8);
    *(float4*)&tabf[t * 8 + 4] = *(const float4*)(grid + t * 8 + 4);
  }
  __syncthreads();

#pragma unroll
  for (int e2 = 0; e2 < 2; ++e2) {
    const int e = t + (e2 << 8);
    const int nl = e >> 3, c = e & 7;
    const unsigned code =
        (unsigned)q[(size_t)(ng * 64 + nl) * QSTRIDE + kg * 8 + c] & 0xffffu;
    const float* tb = &tabf[(code & 255u) * 8];
#pragma unroll
    for (int j = 0; j < 8; ++j) {
      const int bi = __float_as_int(tb[j]) ^ (int)(((code >> (8 + j)) & 1u) << 31);
      tile[nl * 65 + (c << 3) + j] = __int_as_float(bi);
    }
  }
  __syncthreads();

  {
    const int k = t & 63, p = t >> 6;
    float v[16];
#pragma unroll
    for (int j = 0; j < 16; ++j) v[j] = tile[(16 * p + j) * 65 + k];
    fht16(v);
#pragma unroll
    for (int j = 0; j < 16; ++j) tile[(16 * p + j) * 65 + k] = v[j];
  }
  __syncthreads();

  {
    const int k = t & 63, base = (t >> 6) << 2;
#pragma unroll
    for (int bb = 0; bb < 4; ++bb) {
      const int low = base + bb;
      float v0 = tile[(low) * 65 + k],      v1 = tile[(low + 16) * 65 + k];
      float v2 = tile[(low + 32) * 65 + k], v3 = tile[(low + 48) * 65 + k];
      fht4(v0, v1, v2, v3);
      tile[(low) * 65 + k] = v0;      tile[(low + 16) * 65 + k] = v1;
      tile[(low + 32) * 65 + k] = v2; tile[(low + 48) * 65 + k] = v3;
    }
  }
  __syncthreads();

  {
    const int nl = t >> 2, koff = (t & 3) << 4;
    union { f16 h[16]; int4 v[2]; } u;
#pragma unroll
    for (int i = 0; i < 16; ++i) u.h[i] = (f16)tile[nl * 65 + koff + i];
    int4* dst = (int4*)(Wp + (size_t)(ng * 64 + nl) * N_FEAT + kg * 64 + koff);
    dst[0] = u.v[0];
    dst[1] = u.v[1];
  }
}

// ---------------------------------------------------------------------------
// Kernel 3: pass B — H64 over n bits 6..11, in place on Wp.
// ---------------------------------------------------------------------------
__global__ __launch_bounds__(256) void k_wB(f16* __restrict__ Wp) {
  __shared__ float tile[64 * 65];
  const int t = threadIdx.x;
  const int kg = blockIdx.x;
  const int n0 = blockIdx.y;
  {
    const int n1 = t >> 2, koff = (t & 3) << 4;
    const f16* src = Wp + (size_t)(n0 + 64 * n1) * N_FEAT + kg * 64 + koff;
    union { f16 h[16]; int4 v[2]; } u;
    u.v[0] = ((const int4*)src)[0];
    u.v[1] = ((const int4*)src)[1];
#pragma unroll
    for (int i = 0; i < 16; ++i) tile[n1 * 65 + koff + i] = (float)u.h[i];
  }
  __syncthreads();
  {
    const int k = t & 63, p = t >> 6;
    float v[16];
#pragma unroll
    for (int j = 0; j < 16; ++j) v[j] = tile[(16 * p + j) * 65 + k];
    fht16(v);
#pragma unroll
    for (int j = 0; j < 16; ++j) tile[(16 * p + j) * 65 + k] = v[j];
  }
  __syncthreads();
  {
    const int k = t & 63, base = (t >> 6) << 2;
#pragma unroll
    for (int bb = 0; bb < 4; ++bb) {
      const int low = base + bb;
      float v0 = tile[(low) * 65 + k],      v1 = tile[(low + 16) * 65 + k];
      float v2 = tile[(low + 32) * 65 + k], v3 = tile[(low + 48) * 65 + k];
      fht4(v0, v1, v2, v3);
      tile[(low) * 65 + k] = v0;      tile[(low + 16) * 65 + k] = v1;
      tile[(low + 32) * 65 + k] = v2; tile[(low + 48) * 65 + k] = v3;
    }
  }
  __syncthreads();
  {
    const int n1 = t >> 2, koff = (t & 3) << 4;
    union { f16 h[16]; int4 v[2]; } u;
#pragma unroll
    for (int i = 0; i < 16; ++i) u.h[i] = (f16)tile[n1 * 65 + koff + i];
    int4* dst = (int4*)(Wp + (size_t)(n0 + 64 * n1) * N_FEAT + kg * 64 + koff);
    dst[0] = u.v[0];
    dst[1] = u.v[1];
  }
}

// ---------------------------------------------------------------------------
// Kernel 4: out[8192,4096](fp32) = (x * W'^T)/64 * SV + bias.
// 256x256 tile, BK=64, 8 waves (2Mx4N), 4-phase K-tile schedule with counted
// vmcnt (never 0 in main loop), raw s_barrier, setprio around MFMA clusters.
// Round-3: + XCD-chunked blockIdx swizzle (T1). 512 wgs, 512%8==0 -> simple
// bijective form; each XCD gets 4 consecutive A-panels x all 16 N-blocks, so
// the 2MB A-panel is reused x16 inside one 4MB per-XCD L2.
//
// Mapping invariant: phase (mh,nh) touches exactly one LDS half per wave.
//   A rows:  m = (mh<<7) + (wr<<6) + (i<<4) + ml   (mh=0 -> h0, mh=1 -> h1)
//   B rows:  n = (nh<<7) + (wc<<5) + (j<<4) + ml   (nh=0 -> h2, nh=1 -> h3)
//
// Per-wave ISSUE ORDER h0, h2, h3, h1 (2 GLD16 each; pinned by asm clobbers
// + sched_barrier(0)).  Wait bookkeeping (per-wave outstanding, induction):
//   enter iter t:            {h3(t),h1(t)}                  = 4
//   P1 stage h0(t+1)         -> 6   (reads lo halves: landed)
//   W_P2 vmcnt(4): h3(t) done (B-hi readable)               -> 4
//   P2 stage h2(t+1)         -> 6
//   W_P3 vmcnt(4): h1(t) done (A-hi readable)               -> 4
//   P3 stage h3(t+1) -> 6;  P4 stage h1(t+1) -> 8
//   W_P4e vmcnt(4): h0,h2(t+1) done (next P1 readable)      -> 4
// ---------------------------------------------------------------------------
#define BM 256
#define BN 256
#define BK 64
#define KDIM 4096

#define WAITB(n)                                          \
  asm volatile("s_waitcnt vmcnt(" #n ")" ::: "memory");   \
  __builtin_amdgcn_s_barrier();

#define SCHED_FENCE() __builtin_amdgcn_sched_barrier(0)

// Stage one 128-row x 64-k half: wave w covers rows w*16+i*8..+7 (i=0,1).
#define STAGE_HALF(gbase, lhalf)                                         \
  {                                                                      \
    _Pragma("unroll")                                                    \
    for (int i_ = 0; i_ < 2; ++i_) {                                     \
      const int rb_ = (w << 4) + (i_ << 3);                              \
      const int r_ = rb_ + srow;                                         \
      const int kc_ = scc ^ (r_ & 7);                                    \
      GLD16((gbase) + (size_t)r_ * KDIM + (kc_ << 3), (lhalf) + (rb_ << 6)); \
    }                                                                    \
  }

// A-fragments: 4 m-frags x 2 k-steps from m-half mh of current buffer.
#define LDA(dst, mh)                                                     \
  {                                                                      \
    _Pragma("unroll")                                                    \
    for (int i_ = 0; i_ < 4; ++i_) {                                     \
      const int m_ = ((mh) << 7) + (wr << 6) + (i_ << 4) + ml;           \
      _Pragma("unroll")                                                  \
      for (int s_ = 0; s_ < 2; ++s_) {                                   \
        const int kc_ = ((s_ << 2) + quad) ^ (m_ & 7);                   \
        dst[i_][s_] = *(const f16x8*)&sA[cur][(m_ << 6) + (kc_ << 3)];   \
      }                                                                  \
    }                                                                    \
  }

// B-fragments: 2 n-frags x 2 k-steps from n-half nh of current buffer.
#define LDB(dst, nh)                                                     \
  {                                                                      \
    _Pragma("unroll")                                                    \
    for (int j_ = 0; j_ < 2; ++j_) {                                     \
      const int n_ = ((nh) << 7) + (wc << 5) + (j_ << 4) + ml;           \
      _Pragma("unroll")                                                  \
      for (int s_ = 0; s_ < 2; ++s_) {                                   \
        const int kc_ = ((s_ << 2) + quad) ^ (n_ & 7);                   \
        dst[j_][s_] = *(const f16x8*)&sB[cur][(n_ << 6) + (kc_ << 3)];   \
      }                                                                  \
    }                                                                    \
  }

// One C-quadrant: 4m x 2n frags x 2 k-steps = 16 MFMA, setprio-wrapped.
#define MMAQ(mh, nh)                                                     \
  {                                                                      \
    __builtin_amdgcn_s_setprio(1);                                       \
    _Pragma("unroll")                                                    \
    for (int i_ = 0; i_ < 4; ++i_) {                                     \
      _Pragma("unroll")                                                  \
      for (int j_ = 0; j_ < 2; ++j_) {                                   \
        acc[(mh) * 4 + i_][(nh) * 2 + j_] =                              \
            __builtin_amdgcn_mfma_f32_16x16x32_f16(                      \
                af[i_][0], bf[j_][0], acc[(mh) * 4 + i_][(nh) * 2 + j_], \
                0, 0, 0);                                                \
        acc[(mh) * 4 + i_][(nh) * 2 + j_] =                              \
            __builtin_amdgcn_mfma_f32_16x16x32_f16(                      \
                af[i_][1], bf[j_][1], acc[(mh) * 4 + i_][(nh) * 2 + j_], \
                0, 0, 0);                                                \
      }                                                                  \
    }                                                                    \
    __builtin_amdgcn_s_setprio(0);                                       \
  }

__global__ __launch_bounds__(512, 2) void k_gemm(const f16* __restrict__ A,
                                                 const f16* __restrict__ B,
                                                 float* __restrict__ C,
                                                 const float* __restrict__ SV,
                                                 const float* __restrict__ bias) {
  __shared__ __attribute__((aligned(16))) f16 sA[2][BM * BK];
  __shared__ __attribute__((aligned(16))) f16 sB[2][BN * BK];

  const int tid = threadIdx.x;
  const int lane = tid & 63;
  const int w = tid >> 6;        // 0..7
  const int wr = w >> 2;         // 0..1 : 64-row band within each m-half
  const int wc = w & 3;          // 0..3 : 32-col band within each n-half

  // T1: XCD-chunked bijective swizzle. lin%8 ~ XCD id (HW round-robin);
  // give each XCD 64 consecutive swz ids = 4 m-panels x all 16 n-blocks.
  const int lin = blockIdx.y * gridDim.x + blockIdx.x;  // dispatch order
  const int swz = ((lin & 7) << 6) | (lin >> 3);        // nwg=512, bijective
  const int m0 = (swz >> 4) * BM;
  const int n0 = (swz & 15) * BN;

  const int quad = lane >> 4;
  const int ml = lane & 15;
  const int srow = lane >> 3;    // staging: row within 8-row group
  const int scc = lane & 7;      // staging: chunk (pre-swizzled at source)

  f32x4 acc[8][4];
#pragma unroll
  for (int i = 0; i < 8; ++i)
#pragma unroll
    for (int j = 0; j < 4; ++j) acc[i][j] = (f32x4)0.0f;

  const f16* Ab = A + (size_t)m0 * KDIM;
  const f16* Bb = B + (size_t)n0 * KDIM;

  // Prologue: stage tile 0, issue order h0, h2, h3, h1 (order pinned).
  STAGE_HALF(Ab, &sA[0][0]);                                  // h0(0) A-lo
  SCHED_FENCE();
  STAGE_HALF(Bb, &sB[0][0]);                                  // h2(0) B-lo
  SCHED_FENCE();
  STAGE_HALF(Bb + (size_t)128 * KDIM, &sB[0][128 * 64]);      // h3(0) B-hi
  SCHED_FENCE();
  STAGE_HALF(Ab + (size_t)128 * KDIM, &sA[0][128 * 64]);      // h1(0) A-hi
  WAITB(4);  // h0(0), h2(0) landed; h3(0), h1(0) in flight

  f16x8 af[4][2], bf[2][2];

#pragma unroll 2
  for (int t = 0; t < 64; ++t) {
    const int cur = t & 1;
    const int nxt = cur ^ 1;
    const int kn = ((t + 1) & 63) << 6;  // wrap-stage tile 0 on last iter
    const f16* An = Ab + kn;
    const f16* Bn = Bb + kn;

    // ---- P1: quadrant (m-lo, n-lo) — reads h0(t), h2(t) ----
    STAGE_HALF(An, &sA[nxt][0]);                              // h0(t+1)
    LDA(af, 0);
    LDB(bf, 0);
    MMAQ(0, 0);

    // ---- P2: quadrant (m-lo, n-hi) — unlocks h3(t) ----
    WAITB(4);
    STAGE_HALF(Bn, &sB[nxt][0]);                              // h2(t+1)
    LDB(bf, 1);
    MMAQ(0, 1);

    // ---- P3: quadrant (m-hi, n-hi) — unlocks h1(t) ----
    WAITB(4);
    STAGE_HALF(Bn + (size_t)128 * KDIM, &sB[nxt][128 * 64]);  // h3(t+1)
    LDA(af, 1);
    MMAQ(1, 1);

    // ---- P4: quadrant (m-hi, n-lo) ----
    SCHED_FENCE();  // pin h3(t+1) issue before h1(t+1) issue
    STAGE_HALF(An + (size_t)128 * KDIM, &sA[nxt][128 * 64]);  // h1(t+1)
    LDB(bf, 0);  // re-read n-lo frags (saves 16 VGPRs vs keeping live)
    MMAQ(1, 0);
    WAITB(4);                                                 // h0,h2(t+1)
  }

  // Drain the wrap-staged loads before LDS goes out of scope at endpgm.
  asm volatile("s_waitcnt vmcnt(0)" ::: "memory");

  // ---- epilogue: out = acc*(SV/64) + bias, fp32 stores ----
#pragma unroll
  for (int nj = 0; nj < 4; ++nj) {
    const int col = n0 + ((nj >> 1) << 7) + (wc << 5) + ((nj & 1) << 4) + ml;
    const float sv = SV[col] * 0.015625f;
    const float bs = bias[col];
#pragma unroll
    for (int mi = 0; mi < 8; ++mi) {
      const int rowb =
          m0 + ((mi >> 2) << 7) + (wr << 6) + ((mi & 3) << 4) + (quad << 2);
#pragma unroll
      for (int r = 0; r < 4; ++r)
        C[(size_t)(rowb + r) * N_FEAT + col] = acc[mi][nj][r] * sv + bs;
    }
  }
}

// ---------------------------------------------------------------------------
// Host. Buffer plan:
//   d_ws[0, 64MB)          : x (f16)   — written by fht_in, read by gemm
//   W' (f16, 32MB)         : d_ws[64MB,96MB) when ws_size permits (keeps
//                            d_in pristine -> no harness restore of input);
//                            else falls back to reusing the input buffer
//                            (stream-ordered after fht_in consumed it).
//   d_out                  : final fp32 output, written only by gemm.
// ---------------------------------------------------------------------------
extern "C" void kernel_launch(void* const* d_in, const int* in_sizes, int n_in,
                              void* d_out, int out_size, void* d_ws, size_t ws_size,
                              hipStream_t stream) {
  const float* input = nullptr;
  const int* qidxs = nullptr;
  const float* grid_abs = nullptr;
  const float* wscale = nullptr;
  const float* v4k[3] = {nullptr, nullptr, nullptr};
  int n4 = 0;
  for (int i = 0; i < n_in; ++i) {
    switch (in_sizes[i]) {
      case 33554432: input = (const float*)d_in[i]; break;
      case 2097152:  qidxs = (const int*)d_in[i]; break;
      case 2048:     grid_abs = (const float*)d_in[i]; break;
      case 1:        wscale = (const float*)d_in[i]; break;
      case 4096:     if (n4 < 3) v4k[n4++] = (const float*)d_in[i]; break;
      default: break;
    }
  }
  const float* SU = v4k[0];
  const float* SV = v4k[1];
  const float* bias = v4k[2];

  f16* x = (f16*)d_ws;
  f16* Wp;
  if (ws_size >= (size_t)100663296) {       // 96 MiB: room for x + W'
    Wp = (f16*)((char*)d_ws + 67108864);    // keep input buffer pristine
  } else {
    Wp = (f16*)const_cast<float*>(input);   // reuse input buffer post-FHT
  }
  float* out = (float*)d_out;

  k_fht_in<<<M_ROWS, 256, 0, stream>>>(input, SU, wscale, x);
  dim3 gw(64, 64);
  k_wA<<<gw, 256, 0, stream>>>(qidxs, grid_abs, Wp);
  k_wB<<<gw, 256, 0, stream>>>(Wp);
  dim3 g(N_FEAT / BN, M_ROWS / BM);
  k_gemm<<<g, 512, 0, stream>>>(x, Wp, out, SV, bias);
}

// Round 4
// 486.599 us; speedup vs baseline: 1.1606x; 1.0005x over previous
//
#include <hip/hip_runtime.h>
#include <hip/hip_bf16.h>
#include <stdint.h>

typedef _Float16 f16;
typedef _Float16 f16x8 __attribute__((ext_vector_type(8)));
typedef float f32x4 __attribute__((ext_vector_type(4)));

#define N_FEAT 4096
#define M_ROWS 8192
#define QSTRIDE 512  // IN_FEATURES / 8 codewords per W row

// Async global->LDS, 16B per lane: wave-uniform LDS base, HW adds lane*16.
#define GLD16(gptr, lptr)                                                      \
  __builtin_amdgcn_global_load_lds(                                            \
      (const __attribute__((address_space(1))) void*)(gptr),                   \
      (__attribute__((address_space(3))) void*)(uint32_t)(uintptr_t)(lptr),    \
      16, 0, 0)

// Pad 4 floats per 64: keeps 16B alignment of 4-float groups, <=2-way banks.
#define PAD64(i) ((i) + (((i) >> 6) << 2))

// 4-stage in-register Hadamard butterfly on 16 elements (unnormalized).
__device__ __forceinline__ void fht16(float v[16]) {
#pragma unroll
  for (int h = 1; h < 16; h <<= 1) {
#pragma unroll
    for (int i = 0; i < 16; i += (h << 1)) {
#pragma unroll
      for (int j = 0; j < h; ++j) {
        float a = v[i + j], b = v[i + j + h];
        v[i + j] = a + b;
        v[i + j + h] = a - b;
      }
    }
  }
}

// Component-wise (4 independent transforms) butterfly on f32x4 lanes.
__device__ __forceinline__ void fht16v(f32x4 v[16]) {
#pragma unroll
  for (int h = 1; h < 16; h <<= 1) {
#pragma unroll
    for (int i = 0; i < 16; i += (h << 1)) {
#pragma unroll
      for (int j = 0; j < h; ++j) {
        f32x4 a = v[i + j], b = v[i + j + h];
        v[i + j] = a + b;
        v[i + j + h] = a - b;
      }
    }
  }
}

__device__ __forceinline__ void fht4(float& a, float& b, float& c, float& d) {
  float t0 = a + b, t1 = a - b, t2 = c + d, t3 = c - d;
  a = t0 + t2; b = t1 + t3; c = t0 - t2; d = t1 - t3;
}

// ---------------------------------------------------------------------------
// Kernel 1: x = f16( FHT(input*SU) * Wscale/64 ).  4 rows per block (256thr,
// wave = row plane).  LDS = 4 planes x 4096 fp32 (64KB), XOR-swizzled so all
// three phases are pure conflict-free ds_*_b128:
//   phase1 (bits0..3): in-reg on 16 consecutive cols, b128 writes
//   phase2 (bits4..7): f32x4 gather over 4 adjacent low-cols, componentwise
//   phase3 (bits8..11): same trick + scale + packed f16x4 stores
// Swizzle W(c) = c ^ ((((c>>4)^(c>>8))&7)<<2): verified 8-lanes-per-4-bank
// (minimum) for every phase's access pattern; b128-safe (bits2..4 only,
// constant within each 16B beat).
// ---------------------------------------------------------------------------
#define SWZ(c) ((c) ^ (((((c) >> 4) ^ ((c) >> 8)) & 7) << 2))

__global__ __launch_bounds__(256) void k_fht_in(const float* __restrict__ x,
                                                const float* __restrict__ SU,
                                                const float* __restrict__ wscale,
                                                f16* __restrict__ out) {
  __shared__ __attribute__((aligned(16))) float lds[4 * 4096];
  const int t = threadIdx.x;
  const int rw = t >> 6;  // wave index = row within the 4-row group
  const int u = t & 63;
  const size_t row = (size_t)blockIdx.x * 4 + rw;
  float* pl = &lds[rw << 12];  // this wave's row plane
  const float* xr = x + row * N_FEAT;

  // ---- phase 1: bits 0..3 over 4 groups of 16 consecutive cols ----
#pragma unroll
  for (int g = 0; g < 4; ++g) {
    const int c16 = (g << 10) + (u << 4);
    float v[16];
#pragma unroll
    for (int q = 0; q < 4; ++q) {
      const f32x4 a = *(const f32x4*)(xr + c16 + (q << 2));
      const f32x4 s4 = *(const f32x4*)(SU + c16 + (q << 2));
      const f32x4 m = a * s4;
      v[4 * q + 0] = m[0]; v[4 * q + 1] = m[1];
      v[4 * q + 2] = m[2]; v[4 * q + 3] = m[3];
    }
    fht16(v);
#pragma unroll
    for (int q = 0; q < 4; ++q) {
      const int col = c16 + (q << 2);
      f32x4 wv = {v[4 * q + 0], v[4 * q + 1], v[4 * q + 2], v[4 * q + 3]};
      *(f32x4*)&pl[SWZ(col)] = wv;
    }
  }
  __syncthreads();

  // ---- phase 2: bits 4..7, f32x4 over low cols a4..a4+3 ----
  {
    const int b = u >> 2, a4 = (u & 3) << 2;
    f32x4 v[16];
#pragma unroll
    for (int jj = 0; jj < 16; ++jj)
      v[jj] = *(const f32x4*)&pl[SWZ((b << 8) + (jj << 4) + a4)];
    fht16v(v);
#pragma unroll
    for (int jj = 0; jj < 16; ++jj)
      *(f32x4*)&pl[SWZ((b << 8) + (jj << 4) + a4)] = v[jj];
  }
  __syncthreads();

  // ---- phase 3: bits 8..11, f32x4 over cols q4..q4+3, scale, f16 store ----
  {
    const int q4 = u << 2;
    f32x4 v[16];
#pragma unroll
    for (int j = 0; j < 16; ++j)
      v[j] = *(const f32x4*)&pl[SWZ((j << 8) + q4)];
    fht16v(v);
    const float s = wscale[0] * 0.015625f;  // 1/sqrt(4096) = 1/64
    f16* op = out + row * N_FEAT;
#pragma unroll
    for (int j = 0; j < 16; ++j) {
      union { f16 h[4]; uint2 u2; } pk;
      pk.h[0] = (f16)(v[j][0] * s); pk.h[1] = (f16)(v[j][1] * s);
      pk.h[2] = (f16)(v[j][2] * s); pk.h[3] = (f16)(v[j][3] * s);
      *(uint2*)(op + (j << 8) + q4) = pk.u2;
    }
  }
}

// ---------------------------------------------------------------------------
// Kernel 2: pass A of W' = H*W — decode e8p codes, H64 over low 6 bits of n.
// ---------------------------------------------------------------------------
__global__ __launch_bounds__(256) void k_wA(const int* __restrict__ q,
                                            const float* __restrict__ grid,
                                            f16* __restrict__ Wp) {
  __shared__ float tabf[2048];
  __shared__ float tile[64 * 65];
  const int t = threadIdx.x;
  const int kg = blockIdx.x;
  const int ng = blockIdx.y;
  {
    *(float4*)&tabf[t * 8] = *(const float4*)(grid + t * 8);
    *(float4*)&tabf[t * 8 + 4] = *(const float4*)(grid + t * 8 + 4);
  }
  __syncthreads();

#pragma unroll
  for (int e2 = 0; e2 < 2; ++e2) {
    const int e = t + (e2 << 8);
    const int nl = e >> 3, c = e & 7;
    const unsigned code =
        (unsigned)q[(size_t)(ng * 64 + nl) * QSTRIDE + kg * 8 + c] & 0xffffu;
    const float* tb = &tabf[(code & 255u) * 8];
#pragma unroll
    for (int j = 0; j < 8; ++j) {
      const int bi = __float_as_int(tb[j]) ^ (int)(((code >> (8 + j)) & 1u) << 31);
      tile[nl * 65 + (c << 3) + j] = __int_as_float(bi);
    }
  }
  __syncthreads();

  {
    const int k = t & 63, p = t >> 6;
    float v[16];
#pragma unroll
    for (int j = 0; j < 16; ++j) v[j] = tile[(16 * p + j) * 65 + k];
    fht16(v);
#pragma unroll
    for (int j = 0; j < 16; ++j) tile[(16 * p + j) * 65 + k] = v[j];
  }
  __syncthreads();

  {
    const int k = t & 63, base = (t >> 6) << 2;
#pragma unroll
    for (int bb = 0; bb < 4; ++bb) {
      const int low = base + bb;
      float v0 = tile[(low) * 65 + k],      v1 = tile[(low + 16) * 65 + k];
      float v2 = tile[(low + 32) * 65 + k], v3 = tile[(low + 48) * 65 + k];
      fht4(v0, v1, v2, v3);
      tile[(low) * 65 + k] = v0;      tile[(low + 16) * 65 + k] = v1;
      tile[(low + 32) * 65 + k] = v2; tile[(low + 48) * 65 + k] = v3;
    }
  }
  __syncthreads();

  {
    const int nl = t >> 2, koff = (t & 3) << 4;
    union { f16 h[16]; int4 v[2]; } u;
#pragma unroll
    for (int i = 0; i < 16; ++i) u.h[i] = (f16)tile[nl * 65 + koff + i];
    int4* dst = (int4*)(Wp + (size_t)(ng * 64 + nl) * N_FEAT + kg * 64 + koff);
    dst[0] = u.v[0];
    dst[1] = u.v[1];
  }
}

// ---------------------------------------------------------------------------
// Kernel 3: pass B — H64 over n bits 6..11, in place on Wp.
// ---------------------------------------------------------------------------
__global__ __launch_bounds__(256) void k_wB(f16* __restrict__ Wp) {
  __shared__ float tile[64 * 65];
  const int t = threadIdx.x;
  const int kg = blockIdx.x;
  const int n0 = blockIdx.y;
  {
    const int n1 = t >> 2, koff = (t & 3) << 4;
    const f16* src = Wp + (size_t)(n0 + 64 * n1) * N_FEAT + kg * 64 + koff;
    union { f16 h[16]; int4 v[2]; } u;
    u.v[0] = ((const int4*)src)[0];
    u.v[1] = ((const int4*)src)[1];
#pragma unroll
    for (int i = 0; i < 16; ++i) tile[n1 * 65 + koff + i] = (float)u.h[i];
  }
  __syncthreads();
  {
    const int k = t & 63, p = t >> 6;
    float v[16];
#pragma unroll
    for (int j = 0; j < 16; ++j) v[j] = tile[(16 * p + j) * 65 + k];
    fht16(v);
#pragma unroll
    for (int j = 0; j < 16; ++j) tile[(16 * p + j) * 65 + k] = v[j];
  }
  __syncthreads();
  {
    const int k = t & 63, base = (t >> 6) << 2;
#pragma unroll
    for (int bb = 0; bb < 4; ++bb) {
      const int low = base + bb;
      float v0 = tile[(low) * 65 + k],      v1 = tile[(low + 16) * 65 + k];
      float v2 = tile[(low + 32) * 65 + k], v3 = tile[(low + 48) * 65 + k];
      fht4(v0, v1, v2, v3);
      tile[(low) * 65 + k] = v0;      tile[(low + 16) * 65 + k] = v1;
      tile[(low + 32) * 65 + k] = v2; tile[(low + 48) * 65 + k] = v3;
    }
  }
  __syncthreads();
  {
    const int n1 = t >> 2, koff = (t & 3) << 4;
    union { f16 h[16]; int4 v[2]; } u;
#pragma unroll
    for (int i = 0; i < 16; ++i) u.h[i] = (f16)tile[n1 * 65 + koff + i];
    int4* dst = (int4*)(Wp + (size_t)(n0 + 64 * n1) * N_FEAT + kg * 64 + koff);
    dst[0] = u.v[0];
    dst[1] = u.v[1];
  }
}

// ---------------------------------------------------------------------------
// Kernel 4: out[8192,4096](fp32) = (x * W'^T)/64 * SV + bias.
// 256x256 tile, BK=64, 8 waves (2Mx4N), 4-phase K-tile schedule with counted
// vmcnt (never 0 in main loop), raw s_barrier, setprio around MFMA clusters,
// XCD-chunked blockIdx swizzle. Round-4: keep n-lo B fragments live across
// the K-tile (bflo/bfhi) -> 24 ds_read_b128/wave/K-tile (the minimum).
//
// Mapping invariant: phase (mh,nh) touches exactly one LDS half per wave.
//   A rows:  m = (mh<<7) + (wr<<6) + (i<<4) + ml   (mh=0 -> h0, mh=1 -> h1)
//   B rows:  n = (nh<<7) + (wc<<5) + (j<<4) + ml   (nh=0 -> h2, nh=1 -> h3)
//
// Per-wave ISSUE ORDER h0, h2, h3, h1 (2 GLD16 each; pinned by asm clobbers
// + sched_barrier(0)).  Wait bookkeeping (per-wave outstanding, induction):
//   enter iter t:            {h3(t),h1(t)}                  = 4
//   P1 stage h0(t+1)         -> 6   (reads lo halves: landed)
//   W_P2 vmcnt(4): h3(t) done (B-hi readable)               -> 4
//   P2 stage h2(t+1)         -> 6
//   W_P3 vmcnt(4): h1(t) done (A-hi readable)               -> 4
//   P3 stage h3(t+1) -> 6;  P4 stage h1(t+1) -> 8
//   W_P4e vmcnt(4): h0,h2(t+1) done (next P1 readable)      -> 4
// ---------------------------------------------------------------------------
#define BM 256
#define BN 256
#define BK 64
#define KDIM 4096

#define WAITB(n)                                          \
  asm volatile("s_waitcnt vmcnt(" #n ")" ::: "memory");   \
  __builtin_amdgcn_s_barrier();

#define SCHED_FENCE() __builtin_amdgcn_sched_barrier(0)

// Stage one 128-row x 64-k half: wave w covers rows w*16+i*8..+7 (i=0,1).
#define STAGE_HALF(gbase, lhalf)                                         \
  {                                                                      \
    _Pragma("unroll")                                                    \
    for (int i_ = 0; i_ < 2; ++i_) {                                     \
      const int rb_ = (w << 4) + (i_ << 3);                              \
      const int r_ = rb_ + srow;                                         \
      const int kc_ = scc ^ (r_ & 7);                                    \
      GLD16((gbase) + (size_t)r_ * KDIM + (kc_ << 3), (lhalf) + (rb_ << 6)); \
    }                                                                    \
  }

// A-fragments: 4 m-frags x 2 k-steps from m-half mh of current buffer.
#define LDA(dst, mh)                                                     \
  {                                                                      \
    _Pragma("unroll")                                                    \
    for (int i_ = 0; i_ < 4; ++i_) {                                     \
      const int m_ = ((mh) << 7) + (wr << 6) + (i_ << 4) + ml;           \
      _Pragma("unroll")                                                  \
      for (int s_ = 0; s_ < 2; ++s_) {                                   \
        const int kc_ = ((s_ << 2) + quad) ^ (m_ & 7);                   \
        dst[i_][s_] = *(const f16x8*)&sA[cur][(m_ << 6) + (kc_ << 3)];   \
      }                                                                  \
    }                                                                    \
  }

// B-fragments: 2 n-frags x 2 k-steps from n-half nh of current buffer.
#define LDB(dst, nh)                                                     \
  {                                                                      \
    _Pragma("unroll")                                                    \
    for (int j_ = 0; j_ < 2; ++j_) {                                     \
      const int n_ = ((nh) << 7) + (wc << 5) + (j_ << 4) + ml;           \
      _Pragma("unroll")                                                  \
      for (int s_ = 0; s_ < 2; ++s_) {                                   \
        const int kc_ = ((s_ << 2) + quad) ^ (n_ & 7);                   \
        dst[j_][s_] = *(const f16x8*)&sB[cur][(n_ << 6) + (kc_ << 3)];   \
      }                                                                  \
    }                                                                    \
  }

// One C-quadrant: 4m x 2n frags x 2 k-steps = 16 MFMA, setprio-wrapped.
#define MMAQ(mh, nh, bfx)                                                \
  {                                                                      \
    __builtin_amdgcn_s_setprio(1);                                       \
    _Pragma("unroll")                                                    \
    for (int i_ = 0; i_ < 4; ++i_) {                                     \
      _Pragma("unroll")                                                  \
      for (int j_ = 0; j_ < 2; ++j_) {                                   \
        acc[(mh) * 4 + i_][(nh) * 2 + j_] =                              \
            __builtin_amdgcn_mfma_f32_16x16x32_f16(                      \
                af[i_][0], bfx[j_][0], acc[(mh) * 4 + i_][(nh) * 2 + j_],\
                0, 0, 0);                                                \
        acc[(mh) * 4 + i_][(nh) * 2 + j_] =                              \
            __builtin_amdgcn_mfma_f32_16x16x32_f16(                      \
                af[i_][1], bfx[j_][1], acc[(mh) * 4 + i_][(nh) * 2 + j_],\
                0, 0, 0);                                                \
      }                                                                  \
    }                                                                    \
    __builtin_amdgcn_s_setprio(0);                                       \
  }

__global__ __launch_bounds__(512, 2) void k_gemm(const f16* __restrict__ A,
                                                 const f16* __restrict__ B,
                                                 float* __restrict__ C,
                                                 const float* __restrict__ SV,
                                                 const float* __restrict__ bias) {
  __shared__ __attribute__((aligned(16))) f16 sA[2][BM * BK];
  __shared__ __attribute__((aligned(16))) f16 sB[2][BN * BK];

  const int tid = threadIdx.x;
  const int lane = tid & 63;
  const int w = tid >> 6;        // 0..7
  const int wr = w >> 2;         // 0..1 : 64-row band within each m-half
  const int wc = w & 3;          // 0..3 : 32-col band within each n-half

  // XCD-chunked bijective swizzle (neutral on counters but harmless).
  const int lin = blockIdx.y * gridDim.x + blockIdx.x;  // dispatch order
  const int swz = ((lin & 7) << 6) | (lin >> 3);        // nwg=512, bijective
  const int m0 = (swz >> 4) * BM;
  const int n0 = (swz & 15) * BN;

  const int quad = lane >> 4;
  const int ml = lane & 15;
  const int srow = lane >> 3;    // staging: row within 8-row group
  const int scc = lane & 7;      // staging: chunk (pre-swizzled at source)

  f32x4 acc[8][4];
#pragma unroll
  for (int i = 0; i < 8; ++i)
#pragma unroll
    for (int j = 0; j < 4; ++j) acc[i][j] = (f32x4)0.0f;

  const f16* Ab = A + (size_t)m0 * KDIM;
  const f16* Bb = B + (size_t)n0 * KDIM;

  // Prologue: stage tile 0, issue order h0, h2, h3, h1 (order pinned).
  STAGE_HALF(Ab, &sA[0][0]);                                  // h0(0) A-lo
  SCHED_FENCE();
  STAGE_HALF(Bb, &sB[0][0]);                                  // h2(0) B-lo
  SCHED_FENCE();
  STAGE_HALF(Bb + (size_t)128 * KDIM, &sB[0][128 * 64]);      // h3(0) B-hi
  SCHED_FENCE();
  STAGE_HALF(Ab + (size_t)128 * KDIM, &sA[0][128 * 64]);      // h1(0) A-hi
  WAITB(4);  // h0(0), h2(0) landed; h3(0), h1(0) in flight

  f16x8 af[4][2], bflo[2][2], bfhi[2][2];

#pragma unroll 2
  for (int t = 0; t < 64; ++t) {
    const int cur = t & 1;
    const int nxt = cur ^ 1;
    const int kn = ((t + 1) & 63) << 6;  // wrap-stage tile 0 on last iter
    const f16* An = Ab + kn;
    const f16* Bn = Bb + kn;

    // ---- P1: quadrant (m-lo, n-lo) — reads h0(t), h2(t) ----
    STAGE_HALF(An, &sA[nxt][0]);                              // h0(t+1)
    LDA(af, 0);
    LDB(bflo, 0);
    MMAQ(0, 0, bflo);

    // ---- P2: quadrant (m-lo, n-hi) — unlocks h3(t) ----
    WAITB(4);
    STAGE_HALF(Bn, &sB[nxt][0]);                              // h2(t+1)
    LDB(bfhi, 1);
    MMAQ(0, 1, bfhi);

    // ---- P3: quadrant (m-hi, n-hi) — unlocks h1(t) ----
    WAITB(4);
    STAGE_HALF(Bn + (size_t)128 * KDIM, &sB[nxt][128 * 64]);  // h3(t+1)
    LDA(af, 1);
    MMAQ(1, 1, bfhi);

    // ---- P4: quadrant (m-hi, n-lo) — bflo still live, no re-read ----
    SCHED_FENCE();  // pin h3(t+1) issue before h1(t+1) issue
    STAGE_HALF(An + (size_t)128 * KDIM, &sA[nxt][128 * 64]);  // h1(t+1)
    MMAQ(1, 0, bflo);
    WAITB(4);                                                 // h0,h2(t+1)
  }

  // Drain the wrap-staged loads before LDS goes out of scope at endpgm.
  asm volatile("s_waitcnt vmcnt(0)" ::: "memory");

  // ---- epilogue: out = acc*(SV/64) + bias, fp32 stores ----
#pragma unroll
  for (int nj = 0; nj < 4; ++nj) {
    const int col = n0 + ((nj >> 1) << 7) + (wc << 5) + ((nj & 1) << 4) + ml;
    const float sv = SV[col] * 0.015625f;
    const float bs = bias[col];
#pragma unroll
    for (int mi = 0; mi < 8; ++mi) {
      const int rowb =
          m0 + ((mi >> 2) << 7) + (wr << 6) + ((mi & 3) << 4) + (quad << 2);
#pragma unroll
      for (int r = 0; r < 4; ++r)
        C[(size_t)(rowb + r) * N_FEAT + col] = acc[mi][nj][r] * sv + bs;
    }
  }
}

// ---------------------------------------------------------------------------
// Host. Buffer plan:
//   d_ws[0, 64MB)          : x (f16)   — written by fht_in, read by gemm
//   W' (f16, 32MB)         : d_ws[64MB,96MB) when ws_size permits (keeps
//                            d_in pristine); else reuse the input buffer
//                            (stream-ordered after fht_in consumed it).
//   d_out                  : final fp32 output, written only by gemm.
// ---------------------------------------------------------------------------
extern "C" void kernel_launch(void* const* d_in, const int* in_sizes, int n_in,
                              void* d_out, int out_size, void* d_ws, size_t ws_size,
                              hipStream_t stream) {
  const float* input = nullptr;
  const int* qidxs = nullptr;
  const float* grid_abs = nullptr;
  const float* wscale = nullptr;
  const float* v4k[3] = {nullptr, nullptr, nullptr};
  int n4 = 0;
  for (int i = 0; i < n_in; ++i) {
    switch (in_sizes[i]) {
      case 33554432: input = (const float*)d_in[i]; break;
      case 2097152:  qidxs = (const int*)d_in[i]; break;
      case 2048:     grid_abs = (const float*)d_in[i]; break;
      case 1:        wscale = (const float*)d_in[i]; break;
      case 4096:     if (n4 < 3) v4k[n4++] = (const float*)d_in[i]; break;
      default: break;
    }
  }
  const float* SU = v4k[0];
  const float* SV = v4k[1];
  const float* bias = v4k[2];

  f16* x = (f16*)d_ws;
  f16* Wp;
  if (ws_size >= (size_t)100663296) {       // 96 MiB: room for x + W'
    Wp = (f16*)((char*)d_ws + 67108864);    // keep input buffer pristine
  } else {
    Wp = (f16*)const_cast<float*>(input);   // reuse input buffer post-FHT
  }
  float* out = (float*)d_out;

  k_fht_in<<<M_ROWS / 4, 256, 0, stream>>>(input, SU, wscale, x);
  dim3 gw(64, 64);
  k_wA<<<gw, 256, 0, stream>>>(qidxs, grid_abs, Wp);
  k_wB<<<gw, 256, 0, stream>>>(Wp);
  dim3 g(N_FEAT / BN, M_ROWS / BM);
  k_gemm<<<g, 512, 0, stream>>>(x, Wp, out, SV, bias);
}